// Round 9
// baseline (187.111 us; speedup 1.0000x reference)
//
#include <hip/hip_runtime.h>

#define D 256

typedef float f32x4 __attribute__((ext_vector_type(4)));
typedef short short8 __attribute__((ext_vector_type(8)));
typedef __bf16 bf16x8 __attribute__((ext_vector_type(8)));

static __device__ __forceinline__ short f2bs(float f) {
    __bf16 b = (__bf16)f;
    return __builtin_bit_cast(short, b);
}
static __device__ __forceinline__ float bs2f(short s) {
    unsigned u = ((unsigned)(unsigned short)s) << 16;
    return __builtin_bit_cast(float, u);
}

// async global->LDS, 16B per lane; LDS dest = wave-uniform base + lane*16
static __device__ __forceinline__ void gload_lds16(const short* g, short* l) {
    __builtin_amdgcn_global_load_lds(
        (const __attribute__((address_space(1))) void*)g,
        (__attribute__((address_space(3))) void*)l,
        16, 0, 0);
}

// ---------------- precompute kernels (run every call; deterministic) ----------------

__global__ void pre_bc(const float* __restrict__ b_agg, const float* __restrict__ We1,
                       const float* __restrict__ be1, float* __restrict__ bc)
{
    int j = threadIdx.x;
    float acc = be1[j];
    for (int k = 0; k < D; ++k)
        acc += 2.f * b_agg[k] * We1[k * D + j];
    bc[j] = acc;
}

// Ws[i][k] = W_agg[i*D+k] + W_agg[(i+D)*D+k]; Wc[i][j] = sum_k Ws[i][k]*We1[k][j]
// stored transposed: WcT[j*D+i]
__global__ void pre_wct(const float* __restrict__ W_agg, const float* __restrict__ We1,
                        short* __restrict__ WcT)
{
    __shared__ float wsrow[D];
    int i = blockIdx.x, j = threadIdx.x;
    wsrow[j] = W_agg[i * D + j] + W_agg[(i + D) * D + j];
    __syncthreads();
    float acc = 0.f;
    for (int k = 0; k < D; ++k)
        acc += wsrow[k] * We1[k * D + j];
    WcT[j * D + i] = f2bs(acc);
}

__global__ void pre_wn1t(const float* __restrict__ Wn1, short* __restrict__ Wn1T)
{
    int i = blockIdx.x, j = threadIdx.x;
    Wn1T[j * D + i] = f2bs(Wn1[i * D + j]);
}

__global__ void pre_w2t(const float* __restrict__ We2, const float* __restrict__ Wn2,
                        short* __restrict__ We2T, short* __restrict__ Wn2T)
{
    int k = threadIdx.x;
    for (int c = 0; c < 16; ++c) {
        float ve = (c < 5) ? We2[k * 5 + c] : 0.f;
        float vn = (c < 2) ? Wn2[k * 2 + c] : 0.f;
        We2T[c * D + k] = f2bs(ve);
        Wn2T[c * D + k] = f2bs(vn);
    }
}

// ---------------- node GEMM v4: PINNED register weights, pure-LDS k-loop ----------------
// H' = nf@Wc + bc/2 (bf16 -> ws);  node_res = relu(nf@Wn1+bn1)@Wn2 + bn2 -> out.
// 512 threads = 8 waves; 64 rows/block; 512 cols (waves 0-3: Wc -> H, 4-7: Wn1 -> node).
// Per wave: B = 4 N-tiles x 8 ksteps x short8 = 128 VGPR, loaded once and PINNED with an
// empty inline-asm "+v" fence so the compiler cannot rematerialize the loads inside the
// k-loop (r7 failure: VGPR_Count=104 proved Bw was re-fetched from L2 every MFMA).
// A tile in LDS, fragment-order (conflict-free b128 on both sides).  Epilogue: H half is
// re-packed through sA (reused) and stored with coalesced 16B writes by waves 0-3 while
// waves 4-7 run the node GEMM2.
__global__ __launch_bounds__(512, 2)
void node_h_gemm4(const float* __restrict__ nf,
                  const short* __restrict__ WcT, const short* __restrict__ Wn1T,
                  const float* __restrict__ bc,  const float* __restrict__ bn1,
                  const short* __restrict__ Wn2T, const float* __restrict__ bn2,
                  short* __restrict__ H, float* __restrict__ outn, int nrows)
{
    __shared__ __align__(16) short sA[2048 * 8];  // 32 KB frag-order A; reused as sH
    __shared__ __align__(16) short hl[64 * D];    // 32 KB node-half relu'd h (swizzled)

    const int tid = threadIdx.x;
    const int lane = tid & 63;
    const int w = tid >> 6;        // 0..7
    const int l15 = lane & 15;
    const int g = lane >> 4;
    const int rowblk = blockIdx.x * 64;

    // ---- hoist this wave's weight fragments into registers and PIN them ----
    const short* Wb = (w < 4) ? WcT : Wn1T;
    const int nc0 = (w & 3) * 4;
    short8 Bw[4][8];
#pragma unroll
    for (int t = 0; t < 4; ++t)
#pragma unroll
        for (int ks = 0; ks < 8; ++ks)
            Bw[t][ks] = *reinterpret_cast<const short8*>(
                Wb + ((nc0 + t) * 16 + l15) * D + ks * 32 + g * 8);
#pragma unroll
    for (int t = 0; t < 4; ++t)
#pragma unroll
        for (int ks = 0; ks < 8; ++ks)
            asm volatile("" : "+v"(Bw[t][ks]));   // materialize & keep live

    // ---- stage A: fp32 -> bf16 into fragment-order LDS ----
    // frag i = ks*256 + f*64 + g*16 + l15 holds nf[rowblk+f*16+l15][ks*32+g*8 ..+8]
#pragma unroll
    for (int j = 0; j < 4; ++j) {
        const int i = j * 512 + tid;
        const int li = i & 15, gi = (i >> 4) & 3, fi = (i >> 6) & 3, ki = i >> 8;
        int r = rowblk + fi * 16 + li;
        if (r > nrows - 1) r = nrows - 1;
        const float4* p = reinterpret_cast<const float4*>(nf + (size_t)r * D + ki * 32 + gi * 8);
        float4 x0 = p[0], x1 = p[1];
        bf16x8 v = {(__bf16)x0.x, (__bf16)x0.y, (__bf16)x0.z, (__bf16)x0.w,
                    (__bf16)x1.x, (__bf16)x1.y, (__bf16)x1.z, (__bf16)x1.w};
        *reinterpret_cast<short8*>(&sA[i * 8]) = __builtin_bit_cast(short8, v);
    }
    __syncthreads();

    // ---- k-loop: pure LDS + MFMA (no global ops) ----
    f32x4 acc[4][4];
#pragma unroll
    for (int f = 0; f < 4; ++f)
#pragma unroll
        for (int t = 0; t < 4; ++t)
            acc[f][t] = f32x4{0.f, 0.f, 0.f, 0.f};

#pragma unroll
    for (int ks = 0; ks < 8; ++ks) {
        short8 a[4];
#pragma unroll
        for (int f = 0; f < 4; ++f)
            a[f] = *reinterpret_cast<const short8*>(&sA[(ks * 256 + f * 64 + lane) * 8]);
#pragma unroll
        for (int t = 0; t < 4; ++t)
#pragma unroll
            for (int f = 0; f < 4; ++f)
                acc[f][t] = __builtin_amdgcn_mfma_f32_16x16x32_bf16(a[f], Bw[t][ks], acc[f][t], 0, 0, 0);
    }

    __syncthreads();   // all sA reads done before reuse as sH

    if (w < 4) {
        // ---- H half: sH[row][col] = bf16(acc + 0.5*bc[col]), plain layout in sA ----
        short* sH = sA;
#pragma unroll
        for (int t = 0; t < 4; ++t) {
            const int col = w * 64 + t * 16 + l15;
            const float bb = 0.5f * bc[col];
#pragma unroll
            for (int f = 0; f < 4; ++f)
#pragma unroll
                for (int r = 0; r < 4; ++r) {
                    const int row = f * 16 + g * 4 + r;
                    sH[row * D + col] = f2bs(acc[f][t][r] + bb);
                }
        }
    } else {
        // ---- node half: hl = relu(acc + bn1), chunk-swizzled for GEMM2 ----
#pragma unroll
        for (int t = 0; t < 4; ++t) {
            const int col = (w - 4) * 64 + t * 16 + l15;
            const float bb = bn1[col];
            const int chunk = col >> 3;
#pragma unroll
            for (int f = 0; f < 4; ++f)
#pragma unroll
                for (int r = 0; r < 4; ++r) {
                    const int row = f * 16 + g * 4 + r;
                    float v = fmaxf(acc[f][t][r] + bb, 0.f);
                    hl[row * D + (((chunk ^ (row & 7)) << 3) | (col & 7))] = f2bs(v);
                }
        }
    }

    __syncthreads();

    if (w < 4) {
        // ---- coalesced H store: 2048 x 16B units over threads 0-255, 8 each ----
#pragma unroll
        for (int j = 0; j < 8; ++j) {
            const int u = j * 256 + tid;
            const int row = u >> 5, seg = u & 31;
            if (rowblk + row < nrows)
                *reinterpret_cast<short8*>(H + (size_t)(rowblk + row) * D + seg * 8) =
                    *reinterpret_cast<const short8*>(&sA[u * 8]);
        }
    } else {
        // ---- node GEMM2: h(16x256) @ Wn2(256x16-padded) per wave ----
        const int vr = w - 4;
        const int row = vr * 16 + l15;
        f32x4 a2 = f32x4{0.f, 0.f, 0.f, 0.f};
#pragma unroll
        for (int ks = 0; ks < 8; ++ks) {
            const int k0 = ks * 32 + g * 8;
            const int c = ks * 4 + g;
            short8 bw = *reinterpret_cast<const short8*>(Wn2T + l15 * D + k0);
            short8 ah = *reinterpret_cast<const short8*>(&hl[row * D + ((c ^ (row & 7)) * 8)]);
            a2 = __builtin_amdgcn_mfma_f32_16x16x32_bf16(ah, bw, a2, 0, 0, 0);
        }
        if (l15 < 2) {
            const float b2 = bn2[l15];
#pragma unroll
            for (int r = 0; r < 4; ++r) {
                const int grow = rowblk + vr * 16 + g * 4 + r;
                if (grow < nrows)
                    outn[(size_t)grow * 2 + l15] = a2[r] + b2;
            }
        }
    }
}

// ---------------- edge kernel v2: register-free gather staging ----------------
// out = relu(H'[src]+H'[dst])@We2 + be2.  4 waves x 16 edges = 64 edges/block.
// Per wave: 16 global_load_lds (1 KB each) stage the 16 src + 16 dst rows into a
// PRIVATE 16 KB LDS region (no barrier needed), source pre-XOR-swizzled so the
// ds_read_b128s are bank-uniform.  Weights live in 64 VGPRs.
__global__ __launch_bounds__(256)
void edge_gemv2(const short* __restrict__ H, const int* __restrict__ pair,
                const short* __restrict__ We2T, const float* __restrict__ be2,
                float* __restrict__ out, int nedges)
{
    __shared__ __align__(16) short eb[4][32 * D];   // 64 KB: per-wave 32 rows

    const int lane = threadIdx.x & 63;
    const int w = threadIdx.x >> 6;
    const int l15 = lane & 15;
    const int g = lane >> 4;
    const int base = blockIdx.x * 64 + w * 16;

    short8 Bf[8];
#pragma unroll
    for (int ks = 0; ks < 8; ++ks)
        Bf[ks] = *reinterpret_cast<const short8*>(We2T + l15 * D + ks * 32 + g * 8);

    // pair entries for this wave's 16 edges (lanes 0-31 hold {src,dst} x16)
    int pv = 0;
    {
        int pi = 2 * base + lane;
        const int pmax = 2 * nedges - 1;
        if (lane < 32) pv = pair[pi > pmax ? pmax : pi];
    }

    // stage: inst j fills LDS rows {2j (src), 2j+1 (dst)} of this wave's region.
    // lane<32 -> src row, lane>=32 -> dst row; 16B slot p holds global chunk p^(j&7).
    const int rsub = lane >> 5;
    const int pos = lane & 31;
#pragma unroll
    for (int j = 0; j < 16; ++j) {
        const int ridx = __shfl(pv, 2 * j + rsub);
        const int c = pos ^ (j & 7);
        gload_lds16(H + (size_t)(unsigned)ridx * D + c * 8, &eb[w][(2 * j) * D]);
    }
    asm volatile("s_waitcnt vmcnt(0)" ::: "memory");   // wave-private region: no barrier

    // compute: edge e = l15 -> rows 2e (src), 2e+1 (dst); slot = chunk ^ (e&7)
    f32x4 acc = f32x4{0.f, 0.f, 0.f, 0.f};
#pragma unroll
    for (int ks = 0; ks < 8; ++ks) {
        const int slot = (ks * 4 + g) ^ (l15 & 7);
        short8 sv = *reinterpret_cast<const short8*>(&eb[w][(2 * l15) * D + slot * 8]);
        short8 dv = *reinterpret_cast<const short8*>(&eb[w][(2 * l15 + 1) * D + slot * 8]);
        short8 a;
#pragma unroll
        for (int i = 0; i < 8; ++i)
            a[i] = f2bs(fmaxf(bs2f(sv[i]) + bs2f(dv[i]), 0.f));
        acc = __builtin_amdgcn_mfma_f32_16x16x32_bf16(a, Bf[ks], acc, 0, 0, 0);
    }

    if (l15 < 5) {
        const float b2 = be2[l15];
#pragma unroll
        for (int r = 0; r < 4; ++r) {
            const int ge = base + g * 4 + r;
            if (ge < nedges)
                out[(size_t)ge * 5 + l15] = acc[r] + b2;
        }
    }
}

// ---------------- fallback (fp32 gathers, proven in round 1) ----------------
template<int MODE>
__global__ __launch_bounds__(256, 2)
void fused_mlp(const float* __restrict__ feat,
               const int* __restrict__ pair,
               const short* __restrict__ W1T,
               const float* __restrict__ bias1,
               const short* __restrict__ W2T,
               const float* __restrict__ bias2,
               float* __restrict__ out,
               int nrows, int ncols)
{
    __shared__ short hl[128 * D];

    const int tid = threadIdx.x;
    const int lane = tid & 63;
    const int w = tid >> 6;
    const int l15 = lane & 15;
    const int g = lane >> 4;
    const int rowblk = blockIdx.x * 128 + w * 32;

    const float* ap0[2];
    const float* ap1[2];
#pragma unroll
    for (int f = 0; f < 2; ++f) {
        int r = rowblk + f * 16 + l15;
        if (r > nrows - 1) r = nrows - 1;
        if constexpr (MODE == 0) {
            ap0[f] = feat + (size_t)r * D;
            ap1[f] = nullptr;
        } else {
            ap0[f] = feat + (size_t)pair[2 * r] * D;
            ap1[f] = feat + (size_t)pair[2 * r + 1] * D;
        }
    }

    f32x4 acc[2][16];
#pragma unroll
    for (int f = 0; f < 2; ++f)
#pragma unroll
        for (int t = 0; t < 16; ++t)
            acc[f][t] = f32x4{0.f, 0.f, 0.f, 0.f};

#pragma unroll
    for (int ks = 0; ks < 8; ++ks) {
        const int k0 = ks * 32 + g * 8;
        short8 af[2];
#pragma unroll
        for (int f = 0; f < 2; ++f) {
            const float4* p0 = reinterpret_cast<const float4*>(ap0[f] + k0);
            float4 x0 = p0[0], x1 = p0[1];
            if constexpr (MODE == 1) {
                const float4* p1 = reinterpret_cast<const float4*>(ap1[f] + k0);
                float4 y0 = p1[0], y1 = p1[1];
                x0.x += y0.x; x0.y += y0.y; x0.z += y0.z; x0.w += y0.w;
                x1.x += y1.x; x1.y += y1.y; x1.z += y1.z; x1.w += y1.w;
            }
            bf16x8 bv = {(__bf16)x0.x, (__bf16)x0.y, (__bf16)x0.z, (__bf16)x0.w,
                         (__bf16)x1.x, (__bf16)x1.y, (__bf16)x1.z, (__bf16)x1.w};
            af[f] = __builtin_bit_cast(short8, bv);
        }
#pragma unroll
        for (int t = 0; t < 16; ++t) {
            short8 bw = *reinterpret_cast<const short8*>(W1T + ((t * 16 + l15) * D + k0));
            acc[0][t] = __builtin_amdgcn_mfma_f32_16x16x32_bf16(af[0], bw, acc[0][t], 0, 0, 0);
            acc[1][t] = __builtin_amdgcn_mfma_f32_16x16x32_bf16(af[1], bw, acc[1][t], 0, 0, 0);
        }
    }

#pragma unroll
    for (int t = 0; t < 16; ++t) {
        const int col = t * 16 + l15;
        const float b = bias1[col];
        const int chunk = col >> 3;
#pragma unroll
        for (int f = 0; f < 2; ++f) {
#pragma unroll
            for (int r = 0; r < 4; ++r) {
                const int rl = w * 32 + f * 16 + g * 4 + r;
                float v = fmaxf(acc[f][t][r] + b, 0.f);
                hl[rl * D + ((chunk ^ (rl & 7)) << 3) + (col & 7)] = f2bs(v);
            }
        }
    }

    __syncthreads();

    f32x4 acc2[2];
    acc2[0] = f32x4{0.f, 0.f, 0.f, 0.f};
    acc2[1] = f32x4{0.f, 0.f, 0.f, 0.f};
#pragma unroll
    for (int ks = 0; ks < 8; ++ks) {
        const int k0 = ks * 32 + g * 8;
        const int chunk = k0 >> 3;
        short8 bw = *reinterpret_cast<const short8*>(W2T + (l15 * D + k0));
#pragma unroll
        for (int f = 0; f < 2; ++f) {
            const int rl = w * 32 + f * 16 + l15;
            short8 ah = *reinterpret_cast<const short8*>(&hl[rl * D + ((chunk ^ (rl & 7)) << 3)]);
            acc2[f] = __builtin_amdgcn_mfma_f32_16x16x32_bf16(ah, bw, acc2[f], 0, 0, 0);
        }
    }

    if (l15 < ncols) {
        const float b2 = bias2[l15];
#pragma unroll
        for (int f = 0; f < 2; ++f) {
#pragma unroll
            for (int r = 0; r < 4; ++r) {
                const int grow = rowblk + f * 16 + g * 4 + r;
                if (grow < nrows)
                    out[(size_t)grow * ncols + l15] = acc2[f][r] + b2;
            }
        }
    }
}

// ---------------- launch ----------------

extern "C" void kernel_launch(void* const* d_in, const int* in_sizes, int n_in,
                              void* d_out, int out_size, void* d_ws, size_t ws_size,
                              hipStream_t stream)
{
    const float* node_feat = (const float*)d_in[0];
    const int*   pair_idx  = (const int*)d_in[1];
    const float* W_agg     = (const float*)d_in[2];
    const float* b_agg     = (const float*)d_in[3];
    const float* We1       = (const float*)d_in[4];
    const float* be1       = (const float*)d_in[5];
    const float* We2       = (const float*)d_in[6];
    const float* be2       = (const float*)d_in[7];
    const float* Wn1       = (const float*)d_in[8];
    const float* bn1       = (const float*)d_in[9];
    const float* Wn2       = (const float*)d_in[10];
    const float* bn2       = (const float*)d_in[11];

    const int N = in_sizes[0] / D;   // 100000
    const int E = in_sizes[1] / 2;   // 262144

    float* out = (float*)d_out;
    char*  ws  = (char*)d_ws;

    short* WcT  = (short*)(ws + 0);        // 128 KB   } contiguous -> WT[512][256]
    short* Wn1T = (short*)(ws + 131072);   // 128 KB   }
    short* We2T = (short*)(ws + 262144);   // 8 KB
    short* Wn2T = (short*)(ws + 270336);   // 8 KB
    float* bc   = (float*)(ws + 278528);   // 1 KB
    const size_t H_OFF = 524288;
    short* H = (short*)(ws + H_OFF);       // N*D*2 = 51.2 MB
    const size_t need = H_OFF + (size_t)N * D * 2;

    pre_bc<<<1, 256, 0, stream>>>(b_agg, We1, be1, bc);
    pre_wct<<<D, 256, 0, stream>>>(W_agg, We1, WcT);
    pre_wn1t<<<D, 256, 0, stream>>>(Wn1, Wn1T);
    pre_w2t<<<1, 256, 0, stream>>>(We2, Wn2, We2T, Wn2T);

    if (ws_size >= need) {
        node_h_gemm4<<<(N + 63) / 64, 512, 0, stream>>>(
            node_feat, WcT, Wn1T, bc, bn1, Wn2T, bn2, H, out, N);

        edge_gemv2<<<(E + 63) / 64, 256, 0, stream>>>(
            H, pair_idx, We2T, be2, out + (size_t)2 * N, E);
    } else {
        fused_mlp<0><<<(N + 127) / 128, 256, 0, stream>>>(
            node_feat, nullptr, Wn1T, bn1, Wn2T, bn2, out, N, 2);

        fused_mlp<1><<<E / 128, 256, 0, stream>>>(
            node_feat, pair_idx, WcT, bc, We2T, be2, out + (size_t)2 * N, E, 5);
    }
}

// Round 12
// 166.568 us; speedup vs baseline: 1.1233x; 1.1233x over previous
//
#include <hip/hip_runtime.h>

#define D 256

typedef float f32x4 __attribute__((ext_vector_type(4)));
typedef short short8 __attribute__((ext_vector_type(8)));
typedef __bf16 bf16x8 __attribute__((ext_vector_type(8)));

static __device__ __forceinline__ short f2bs(float f) {
    __bf16 b = (__bf16)f;
    return __builtin_bit_cast(short, b);
}
static __device__ __forceinline__ float bs2f(short s) {
    unsigned u = ((unsigned)(unsigned short)s) << 16;
    return __builtin_bit_cast(float, u);
}

// ---------------- precompute kernels (run every call; deterministic) ----------------

__global__ void pre_bc(const float* __restrict__ b_agg, const float* __restrict__ We1,
                       const float* __restrict__ be1, float* __restrict__ bc)
{
    int j = threadIdx.x;
    float acc = be1[j];
    for (int k = 0; k < D; ++k)
        acc += 2.f * b_agg[k] * We1[k * D + j];
    bc[j] = acc;
}

// Ws[i][k] = W_agg[i*D+k] + W_agg[(i+D)*D+k]; Wc[i][j] = sum_k Ws[i][k]*We1[k][j]
// stored transposed: WcT[j*D+i]
__global__ void pre_wct(const float* __restrict__ W_agg, const float* __restrict__ We1,
                        short* __restrict__ WcT)
{
    __shared__ float wsrow[D];
    int i = blockIdx.x, j = threadIdx.x;
    wsrow[j] = W_agg[i * D + j] + W_agg[(i + D) * D + j];
    __syncthreads();
    float acc = 0.f;
    for (int k = 0; k < D; ++k)
        acc += wsrow[k] * We1[k * D + j];
    WcT[j * D + i] = f2bs(acc);
}

__global__ void pre_wn1t(const float* __restrict__ Wn1, short* __restrict__ Wn1T)
{
    int i = blockIdx.x, j = threadIdx.x;
    Wn1T[j * D + i] = f2bs(Wn1[i * D + j]);
}

__global__ void pre_w2t(const float* __restrict__ We2, const float* __restrict__ Wn2,
                        short* __restrict__ We2T, short* __restrict__ Wn2T)
{
    int k = threadIdx.x;
    for (int c = 0; c < 16; ++c) {
        float ve = (c < 5) ? We2[k * 5 + c] : 0.f;
        float vn = (c < 2) ? Wn2[k * 2 + c] : 0.f;
        We2T[c * D + k] = f2bs(ve);
        Wn2T[c * D + k] = f2bs(vn);
    }
}

// ---------------- node GEMM (r7 structure, PASSED) + explicit B double-buffer ----------------
// H' = nf@Wc + bc/2 (bf16 -> ws);  node_res = relu(nf@Wn1+bn1)@Wn2 + bn2 -> out.
// 512 threads = 8 waves; 64 rows/block; 512 cols (waves 0-3: Wc -> H, 4-7: Wn1 -> node).
// Per wave 4 N-tiles.  B fragments are rotated through TWO register sets (Ba/Bb, 8 live
// frags = 64 VGPR instead of 128): the ks+1 prefetch is issued BEFORE ks's 16 MFMAs, so
// the L2 fetch overlaps MFMA execution and register pressure stays below the compiler's
// rematerialization point (r7 failure: 128-frag array -> remat, VGPR=104, serialized L2
// round trip per k-step).  A tile in LDS, fragment-order (conflict-free b128 both sides).
__global__ __launch_bounds__(512, 2)
void node_h_gemm2b(const float* __restrict__ nf,
                   const short* __restrict__ WcT, const short* __restrict__ Wn1T,
                   const float* __restrict__ bc,  const float* __restrict__ bn1,
                   const short* __restrict__ Wn2T, const float* __restrict__ bn2,
                   short* __restrict__ H, float* __restrict__ outn, int nrows)
{
    __shared__ __align__(16) short sA[2048 * 8];  // 32 KB, fragment-order A tile
    __shared__ __align__(16) short hl[64 * D];    // 32 KB, node-half relu'd h (swizzled)

    const int tid = threadIdx.x;
    const int lane = tid & 63;
    const int w = tid >> 6;        // 0..7
    const int l15 = lane & 15;
    const int g = lane >> 4;
    const int rowblk = blockIdx.x * 64;

    const short* Wb = (w < 4) ? WcT : Wn1T;
    const int nc0 = (w & 3) * 4;
    // B-frag pointer for (t, ks):
    auto bptr = [&](int t, int ks) {
        return reinterpret_cast<const short8*>(
            Wb + ((nc0 + t) * 16 + l15) * D + ks * 32 + g * 8);
    };

    // ---- stage A: fp32 -> bf16 into fragment-order LDS ----
    // frag i = ks*256 + f*64 + g*16 + l15 holds nf[row=rowblk+f*16+l15][ks*32+g*8 .. +8]
#pragma unroll
    for (int j = 0; j < 4; ++j) {
        const int i = j * 512 + tid;
        const int li = i & 15, gi = (i >> 4) & 3, fi = (i >> 6) & 3, ki = i >> 8;
        int r = rowblk + fi * 16 + li;
        if (r > nrows - 1) r = nrows - 1;
        const float4* p = reinterpret_cast<const float4*>(nf + (size_t)r * D + ki * 32 + gi * 8);
        float4 x0 = p[0], x1 = p[1];
        bf16x8 v = {(__bf16)x0.x, (__bf16)x0.y, (__bf16)x0.z, (__bf16)x0.w,
                    (__bf16)x1.x, (__bf16)x1.y, (__bf16)x1.z, (__bf16)x1.w};
        *reinterpret_cast<short8*>(&sA[i * 8]) = __builtin_bit_cast(short8, v);
    }
    __syncthreads();

    // ---- k-loop with 2-deep B rotation ----
    f32x4 acc[4][4];
#pragma unroll
    for (int f = 0; f < 4; ++f)
#pragma unroll
        for (int t = 0; t < 4; ++t)
            acc[f][t] = f32x4{0.f, 0.f, 0.f, 0.f};

    short8 Ba[4], Bb[4];
#pragma unroll
    for (int t = 0; t < 4; ++t) Ba[t] = *bptr(t, 0);

#pragma unroll
    for (int ks = 0; ks < 8; ++ks) {
        short8 a[4];
#pragma unroll
        for (int f = 0; f < 4; ++f)
            a[f] = *reinterpret_cast<const short8*>(&sA[(ks * 256 + f * 64 + lane) * 8]);
        if ((ks & 1) == 0) {
            if (ks < 7) {
#pragma unroll
                for (int t = 0; t < 4; ++t) Bb[t] = *bptr(t, ks + 1);
            }
#pragma unroll
            for (int t = 0; t < 4; ++t)
#pragma unroll
                for (int f = 0; f < 4; ++f)
                    acc[f][t] = __builtin_amdgcn_mfma_f32_16x16x32_bf16(a[f], Ba[t], acc[f][t], 0, 0, 0);
        } else {
            if (ks < 7) {
#pragma unroll
                for (int t = 0; t < 4; ++t) Ba[t] = *bptr(t, ks + 1);
            }
#pragma unroll
            for (int t = 0; t < 4; ++t)
#pragma unroll
                for (int f = 0; f < 4; ++f)
                    acc[f][t] = __builtin_amdgcn_mfma_f32_16x16x32_bf16(a[f], Bb[t], acc[f][t], 0, 0, 0);
        }
    }

    // ---- epilogue: verbatim r7 (PASSED on hardware) ----
    if (w < 4) {
        // H half: H[row][col] = bf16(acc + 0.5*bc[col]), direct global scatter
#pragma unroll
        for (int t = 0; t < 4; ++t) {
            const int col = w * 64 + t * 16 + l15;
            const float bb = 0.5f * bc[col];
#pragma unroll
            for (int f = 0; f < 4; ++f)
#pragma unroll
                for (int r = 0; r < 4; ++r) {
                    const int grow = rowblk + f * 16 + g * 4 + r;
                    if (grow < nrows)
                        H[(size_t)grow * D + col] = f2bs(acc[f][t][r] + bb);
                }
        }
    } else {
        // node half: hl = relu(acc + bn1), chunk-swizzled for GEMM2
#pragma unroll
        for (int t = 0; t < 4; ++t) {
            const int col = (w - 4) * 64 + t * 16 + l15;
            const float bb = bn1[col];
            const int chunk = col >> 3;
#pragma unroll
            for (int f = 0; f < 4; ++f)
#pragma unroll
                for (int r = 0; r < 4; ++r) {
                    const int row = f * 16 + g * 4 + r;
                    float v = fmaxf(acc[f][t][r] + bb, 0.f);
                    hl[row * D + (((chunk ^ (row & 7)) << 3) | (col & 7))] = f2bs(v);
                }
        }
    }

    __syncthreads();

    if (w >= 4) {
        // node GEMM2: h(16x256) @ Wn2(256x16-padded) per wave
        const int vr = w - 4;
        const int row = vr * 16 + l15;
        f32x4 a2 = f32x4{0.f, 0.f, 0.f, 0.f};
#pragma unroll
        for (int ks = 0; ks < 8; ++ks) {
            const int k0 = ks * 32 + g * 8;
            const int c = ks * 4 + g;
            short8 bw = *reinterpret_cast<const short8*>(Wn2T + l15 * D + k0);
            short8 ah = *reinterpret_cast<const short8*>(&hl[row * D + ((c ^ (row & 7)) * 8)]);
            a2 = __builtin_amdgcn_mfma_f32_16x16x32_bf16(ah, bw, a2, 0, 0, 0);
        }
        if (l15 < 2) {
            const float b2 = bn2[l15];
#pragma unroll
            for (int r = 0; r < 4; ++r) {
                const int grow = rowblk + vr * 16 + g * 4 + r;
                if (grow < nrows)
                    outn[(size_t)grow * 2 + l15] = a2[r] + b2;
            }
        }
    }
}

// ---------------- edge kernel: out = relu(H[src]+H[dst])@We2 + be2 (r6, PASSED) ----------
// No LDS.  4 waves x 4 groups x 16 edges = 256 edges/block.  Per group: 16 gather
// loads (16B/lane) issued up front, fp32 add+relu+cvt in regs, 8 MFMAs vs
// register-resident We2T fragments.  Pure gather-BW bound (H is L3-resident).
__global__ __launch_bounds__(256, 4)
void edge_gemv(const short* __restrict__ H, const int* __restrict__ pair,
               const short* __restrict__ We2T, const float* __restrict__ be2,
               float* __restrict__ out, int nedges)
{
    const int lane = threadIdx.x & 63;
    const int w = threadIdx.x >> 6;
    const int l15 = lane & 15;
    const int g = lane >> 4;

    short8 Bf[8];
#pragma unroll
    for (int ks = 0; ks < 8; ++ks)
        Bf[ks] = *reinterpret_cast<const short8*>(We2T + l15 * D + ks * 32 + g * 8);

    const float b2 = (l15 < 5) ? be2[l15] : 0.f;
    const int base = blockIdx.x * 256 + w * 64;

#pragma unroll
    for (int grp = 0; grp < 4; ++grp) {
        int e = base + grp * 16 + l15;
        if (e > nedges - 1) e = nedges - 1;
        const size_t si = (size_t)(unsigned)pair[2 * e];
        const size_t di = (size_t)(unsigned)pair[2 * e + 1];
        const short8* sp = reinterpret_cast<const short8*>(H + si * D + g * 8);
        const short8* dp = reinterpret_cast<const short8*>(H + di * D + g * 8);
        short8 sv[8], dv[8];
#pragma unroll
        for (int ks = 0; ks < 8; ++ks) {
            sv[ks] = sp[ks * 4];
            dv[ks] = dp[ks * 4];
        }
        f32x4 acc = f32x4{0.f, 0.f, 0.f, 0.f};
#pragma unroll
        for (int ks = 0; ks < 8; ++ks) {
            short8 a;
#pragma unroll
            for (int i = 0; i < 8; ++i)
                a[i] = f2bs(fmaxf(bs2f(sv[ks][i]) + bs2f(dv[ks][i]), 0.f));
            acc = __builtin_amdgcn_mfma_f32_16x16x32_bf16(a, Bf[ks], acc, 0, 0, 0);
        }
        if (l15 < 5) {
#pragma unroll
            for (int r = 0; r < 4; ++r) {
                const int ge = base + grp * 16 + g * 4 + r;
                if (ge < nedges)
                    out[(size_t)ge * 5 + l15] = acc[r] + b2;
            }
        }
    }
}

// ---------------- fallback (fp32 gathers, proven in round 1) ----------------
template<int MODE>
__global__ __launch_bounds__(256, 2)
void fused_mlp(const float* __restrict__ feat,
               const int* __restrict__ pair,
               const short* __restrict__ W1T,
               const float* __restrict__ bias1,
               const short* __restrict__ W2T,
               const float* __restrict__ bias2,
               float* __restrict__ out,
               int nrows, int ncols)
{
    __shared__ short hl[128 * D];

    const int tid = threadIdx.x;
    const int lane = tid & 63;
    const int w = tid >> 6;
    const int l15 = lane & 15;
    const int g = lane >> 4;
    const int rowblk = blockIdx.x * 128 + w * 32;

    const float* ap0[2];
    const float* ap1[2];
#pragma unroll
    for (int f = 0; f < 2; ++f) {
        int r = rowblk + f * 16 + l15;
        if (r > nrows - 1) r = nrows - 1;
        if constexpr (MODE == 0) {
            ap0[f] = feat + (size_t)r * D;
            ap1[f] = nullptr;
        } else {
            ap0[f] = feat + (size_t)pair[2 * r] * D;
            ap1[f] = feat + (size_t)pair[2 * r + 1] * D;
        }
    }

    f32x4 acc[2][16];
#pragma unroll
    for (int f = 0; f < 2; ++f)
#pragma unroll
        for (int t = 0; t < 16; ++t)
            acc[f][t] = f32x4{0.f, 0.f, 0.f, 0.f};

#pragma unroll
    for (int ks = 0; ks < 8; ++ks) {
        const int k0 = ks * 32 + g * 8;
        short8 af[2];
#pragma unroll
        for (int f = 0; f < 2; ++f) {
            const float4* p0 = reinterpret_cast<const float4*>(ap0[f] + k0);
            float4 x0 = p0[0], x1 = p0[1];
            if constexpr (MODE == 1) {
                const float4* p1 = reinterpret_cast<const float4*>(ap1[f] + k0);
                float4 y0 = p1[0], y1 = p1[1];
                x0.x += y0.x; x0.y += y0.y; x0.z += y0.z; x0.w += y0.w;
                x1.x += y1.x; x1.y += y1.y; x1.z += y1.z; x1.w += y1.w;
            }
            bf16x8 bv = {(__bf16)x0.x, (__bf16)x0.y, (__bf16)x0.z, (__bf16)x0.w,
                         (__bf16)x1.x, (__bf16)x1.y, (__bf16)x1.z, (__bf16)x1.w};
            af[f] = __builtin_bit_cast(short8, bv);
        }
#pragma unroll
        for (int t = 0; t < 16; ++t) {
            short8 bw = *reinterpret_cast<const short8*>(W1T + ((t * 16 + l15) * D + k0));
            acc[0][t] = __builtin_amdgcn_mfma_f32_16x16x32_bf16(af[0], bw, acc[0][t], 0, 0, 0);
            acc[1][t] = __builtin_amdgcn_mfma_f32_16x16x32_bf16(af[1], bw, acc[1][t], 0, 0, 0);
        }
    }

#pragma unroll
    for (int t = 0; t < 16; ++t) {
        const int col = t * 16 + l15;
        const float b = bias1[col];
        const int chunk = col >> 3;
#pragma unroll
        for (int f = 0; f < 2; ++f) {
#pragma unroll
            for (int r = 0; r < 4; ++r) {
                const int rl = w * 32 + f * 16 + g * 4 + r;
                float v = fmaxf(acc[f][t][r] + b, 0.f);
                hl[rl * D + ((chunk ^ (rl & 7)) << 3) + (col & 7)] = f2bs(v);
            }
        }
    }

    __syncthreads();

    f32x4 acc2[2];
    acc2[0] = f32x4{0.f, 0.f, 0.f, 0.f};
    acc2[1] = f32x4{0.f, 0.f, 0.f, 0.f};
#pragma unroll
    for (int ks = 0; ks < 8; ++ks) {
        const int k0 = ks * 32 + g * 8;
        const int chunk = k0 >> 3;
        short8 bw = *reinterpret_cast<const short8*>(W2T + (l15 * D + k0));
#pragma unroll
        for (int f = 0; f < 2; ++f) {
            const int rl = w * 32 + f * 16 + l15;
            short8 ah = *reinterpret_cast<const short8*>(&hl[rl * D + ((chunk ^ (rl & 7)) << 3)]);
            acc2[f] = __builtin_amdgcn_mfma_f32_16x16x32_bf16(ah, bw, acc2[f], 0, 0, 0);
        }
    }

    if (l15 < ncols) {
        const float b2 = bias2[l15];
#pragma unroll
        for (int f = 0; f < 2; ++f) {
#pragma unroll
            for (int r = 0; r < 4; ++r) {
                const int grow = rowblk + f * 16 + g * 4 + r;
                if (grow < nrows)
                    out[(size_t)grow * ncols + l15] = acc2[f][r] + b2;
            }
        }
    }
}

// ---------------- launch ----------------

extern "C" void kernel_launch(void* const* d_in, const int* in_sizes, int n_in,
                              void* d_out, int out_size, void* d_ws, size_t ws_size,
                              hipStream_t stream)
{
    const float* node_feat = (const float*)d_in[0];
    const int*   pair_idx  = (const int*)d_in[1];
    const float* W_agg     = (const float*)d_in[2];
    const float* b_agg     = (const float*)d_in[3];
    const float* We1       = (const float*)d_in[4];
    const float* be1       = (const float*)d_in[5];
    const float* We2       = (const float*)d_in[6];
    const float* be2       = (const float*)d_in[7];
    const float* Wn1       = (const float*)d_in[8];
    const float* bn1       = (const float*)d_in[9];
    const float* Wn2       = (const float*)d_in[10];
    const float* bn2       = (const float*)d_in[11];

    const int N = in_sizes[0] / D;   // 100000
    const int E = in_sizes[1] / 2;   // 262144

    float* out = (float*)d_out;
    char*  ws  = (char*)d_ws;

    short* WcT  = (short*)(ws + 0);        // 128 KB
    short* Wn1T = (short*)(ws + 131072);   // 128 KB
    short* We2T = (short*)(ws + 262144);   // 8 KB
    short* Wn2T = (short*)(ws + 270336);   // 8 KB
    float* bc   = (float*)(ws + 278528);   // 1 KB
    const size_t H_OFF = 524288;
    short* H = (short*)(ws + H_OFF);       // N*D*2 = 51.2 MB
    const size_t need = H_OFF + (size_t)N * D * 2;

    pre_bc<<<1, 256, 0, stream>>>(b_agg, We1, be1, bc);
    pre_wct<<<D, 256, 0, stream>>>(W_agg, We1, WcT);
    pre_wn1t<<<D, 256, 0, stream>>>(Wn1, Wn1T);
    pre_w2t<<<1, 256, 0, stream>>>(We2, Wn2, We2T, Wn2T);

    if (ws_size >= need) {
        node_h_gemm2b<<<(N + 63) / 64, 512, 0, stream>>>(
            node_feat, WcT, Wn1T, bc, bn1, Wn2T, bn2, H, out, N);

        edge_gemv<<<(E + 255) / 256, 256, 0, stream>>>(
            H, pair_idx, We2T, be2, out + (size_t)2 * N, E);
    } else {
        fused_mlp<0><<<(N + 127) / 128, 256, 0, stream>>>(
            node_feat, nullptr, Wn1T, bn1, Wn2T, bn2, out, N, 2);

        fused_mlp<1><<<E / 128, 256, 0, stream>>>(
            node_feat, pair_idx, WcT, bc, We2T, be2, out + (size_t)2 * N, E, 5);
    }
}